// Round 1
// baseline (277.955 us; speedup 1.0000x reference)
//
#include <hip/hip_runtime.h>
#include <math.h>

// SimpleRetention, MI355X fp32 baseline.
// out = (Q K^T ∘ D) V,  D[n,m] = gamma^(n-m) for n>=m else 0, gamma = 0.96875.
// gamma^513 ~ 8e-8  ->  banded computation with window of 8 previous 64-tiles
// + diagonal tile is exact to ~1e-8 (threshold is 1.12e-3).

#define SEQ    4096
#define NBATCH 4
#define HID    256
#define HD     64
#define WTILES 8   // previous tiles in band (+ diagonal): min excluded distance 513

// ---------------------------------------------------------------------------
// Kernel A: fused projection (X @ {WQ,WK,WV}) + xPos rotation/scale.
// 512 blocks x 256 threads, 32 rows per block.
// ---------------------------------------------------------------------------
__global__ __launch_bounds__(256)
void proj_xpos_kernel(const float* __restrict__ X,
                      const float* __restrict__ WQ,
                      const float* __restrict__ WK,
                      const float* __restrict__ WV,
                      float* __restrict__ Qo,
                      float* __restrict__ Ko,
                      float* __restrict__ Vo)
{
    __shared__ __align__(16) float Xs[32 * 260];   // stride 260: 16B-aligned rows
    const int t = threadIdx.x;
    const long long row0 = (long long)blockIdx.x * 32;

    // stage 32x256 X tile (float4, coalesced)
    for (int e = t; e < 32 * 64; e += 256) {
        const int r  = e >> 6;
        const int k4 = (e & 63) << 2;
        *reinterpret_cast<float4*>(&Xs[r * 260 + k4]) =
            *reinterpret_cast<const float4*>(&X[(row0 + r) * HID + k4]);
    }
    __syncthreads();

    const int ty = t >> 6;   // 0..3
    const int tx = t & 63;   // output column within each of Q/K/V
    float accQ[8], accK[8], accV[8];
#pragma unroll
    for (int i = 0; i < 8; ++i) { accQ[i] = 0.f; accK[i] = 0.f; accV[i] = 0.f; }

    // rows owned: r = ty + 4*i  (strided -> Xs reads are wave-uniform broadcasts)
    for (int k0 = 0; k0 < HID; k0 += 4) {
        float4 xv[8];
#pragma unroll
        for (int i = 0; i < 8; ++i)
            xv[i] = *reinterpret_cast<const float4*>(&Xs[(ty + 4 * i) * 260 + k0]);
#pragma unroll
        for (int kk = 0; kk < 4; ++kk) {
            const float wq = WQ[(k0 + kk) * HD + tx];   // coalesced, L1-hot
            const float wk = WK[(k0 + kk) * HD + tx];
            const float wv = WV[(k0 + kk) * HD + tx];
#pragma unroll
            for (int i = 0; i < 8; ++i) {
                const float x = (&xv[i].x)[kk];         // kk is unrolled/static
                accQ[i] = fmaf(x, wq, accQ[i]);
                accK[i] = fmaf(x, wk, accK[i]);
                accV[i] = fmaf(x, wv, accV[i]);
            }
        }
    }

    // V needs no rotation
#pragma unroll
    for (int i = 0; i < 8; ++i)
        Vo[(row0 + ty + 4 * i) * HD + tx] = accV[i];

    __syncthreads();          // done with Xs as X-tile
    float* Raw = Xs;          // reuse as 32 x 130 raw (Q | K) buffer
#pragma unroll
    for (int i = 0; i < 8; ++i) {
        Raw[(ty + 4 * i) * 130 + tx]      = accQ[i];
        Raw[(ty + 4 * i) * 130 + 64 + tx] = accK[i];
    }
    __syncthreads();

    // xPos: pairs (2i, 2i+1). 32 rows * 64 pair-tasks (Q:0..31, K:32..63).
    for (int p = t; p < 32 * 64; p += 256) {
        const int r   = p >> 6;
        const int c   = p & 63;
        const bool isK = (c >= 32);
        const int i   = c & 31;
        const int n   = (int)((row0 + r) & (SEQ - 1));  // position within sequence

        // scale_vec = (2i + 0.4*64)/(1.4*64); scale = sv^(n/512); K uses 1/scale
        const float sv = (2.f * (float)i + 25.6f) / 89.6f;
        float scale = powf(sv, (float)n * (1.f / 512.f));
        if (isK) scale = 1.f / scale;

        // inv_freq = 1/10000^(i/32)  (accurate libm to track np reference)
        const float inv_freq = 1.f / powf(10000.f, (float)i * (1.f / 32.f));
        const float th = (float)n * inv_freq;
        float sn, cs;
        sincosf(th, &sn, &cs);
        sn *= scale; cs *= scale;

        const int base = isK ? 64 : 0;
        const float x1 = Raw[r * 130 + base + 2 * i];
        const float x2 = Raw[r * 130 + base + 2 * i + 1];
        const float o1 = x1 * cs - x2 * sn;
        const float o2 = x2 * cs + x1 * sn;
        float* P = isK ? Ko : Qo;
        *reinterpret_cast<float2*>(&P[(row0 + r) * HD + 2 * i]) = make_float2(o1, o2);
    }
}

// ---------------------------------------------------------------------------
// Kernel B: banded retention. grid (SEQ/64, NBATCH) = 256 blocks (1/CU),
// 256 threads, 4x4 strided register micro-tiles.
// ---------------------------------------------------------------------------
__global__ __launch_bounds__(256)
void retention_kernel(const float* __restrict__ Qw,
                      const float* __restrict__ Kw,
                      const float* __restrict__ Vw,
                      float* __restrict__ Out)
{
    __shared__ __align__(16) float Qs[64 * 68];
    __shared__ __align__(16) float Ks[64 * 68];
    __shared__ __align__(16) float Ss[64 * 68];
    __shared__ float Vs[64 * 65];

    const int t  = threadIdx.x;
    const int ty = t >> 4;    // 0..15 (rows r = ty + 16*i)
    const int tx = t & 15;    // 0..15 (cols c = tx + 16*j)
    const int nt = blockIdx.x;
    const int b  = blockIdx.y;
    const int n0 = nt * 64;
    const long long bbase = (long long)b * SEQ;

    // stage Q tile once
    for (int e = t; e < 64 * 64; e += 256) {
        const int r = e >> 6, k = e & 63;
        Qs[r * 68 + k] = Qw[(bbase + n0 + r) * HD + k];
    }

    float O[4][4];
#pragma unroll
    for (int i = 0; i < 4; ++i)
#pragma unroll
        for (int j = 0; j < 4; ++j) O[i][j] = 0.f;

    const float log2g = -0.0458036745f;   // log2(0.96875)
    const int mt0 = (nt >= WTILES) ? (nt - WTILES) : 0;

    for (int mt = mt0; mt <= nt; ++mt) {
        const int m0 = mt * 64;
        __syncthreads();   // Ks/Vs/Ss reusable; also fences initial Q staging
        for (int e = t; e < 64 * 64; e += 256) {
            const int r = e >> 6, k = e & 63;
            Ks[r * 68 + k] = Kw[(bbase + m0 + r) * HD + k];
            Vs[r * 65 + k] = Vw[(bbase + m0 + r) * HD + k];
        }
        __syncthreads();

        // ---- S = Q K^T (64x64x64) ----
        float acc[4][4];
#pragma unroll
        for (int i = 0; i < 4; ++i)
#pragma unroll
            for (int j = 0; j < 4; ++j) acc[i][j] = 0.f;

        for (int k0 = 0; k0 < 64; k0 += 4) {
            float4 qv[4], kv[4];
#pragma unroll
            for (int i = 0; i < 4; ++i)
                qv[i] = *reinterpret_cast<const float4*>(&Qs[(ty + 16 * i) * 68 + k0]);
#pragma unroll
            for (int j = 0; j < 4; ++j)
                kv[j] = *reinterpret_cast<const float4*>(&Ks[(tx + 16 * j) * 68 + k0]);
#pragma unroll
            for (int i = 0; i < 4; ++i)
#pragma unroll
                for (int j = 0; j < 4; ++j) {
                    acc[i][j] = fmaf(qv[i].x, kv[j].x, acc[i][j]);
                    acc[i][j] = fmaf(qv[i].y, kv[j].y, acc[i][j]);
                    acc[i][j] = fmaf(qv[i].z, kv[j].z, acc[i][j]);
                    acc[i][j] = fmaf(qv[i].w, kv[j].w, acc[i][j]);
                }
        }

        // ---- decay + causal mask, stage S ----
#pragma unroll
        for (int i = 0; i < 4; ++i) {
            const int r = ty + 16 * i;
#pragma unroll
            for (int j = 0; j < 4; ++j) {
                const int mm = tx + 16 * j;
                const int d  = (n0 + r) - (m0 + mm);   // >=1 always for mt<nt
                const float g = exp2f((float)d * log2g);
                Ss[r * 68 + mm] = (d >= 0) ? acc[i][j] * g : 0.f;
            }
        }
        __syncthreads();

        // ---- O += S V ----
        for (int m0k = 0; m0k < 64; m0k += 4) {
            float4 sv4[4];
#pragma unroll
            for (int i = 0; i < 4; ++i)
                sv4[i] = *reinterpret_cast<const float4*>(&Ss[(ty + 16 * i) * 68 + m0k]);
#pragma unroll
            for (int mm = 0; mm < 4; ++mm) {
                float vv[4];
#pragma unroll
                for (int j = 0; j < 4; ++j)
                    vv[j] = Vs[(m0k + mm) * 65 + tx + 16 * j];
#pragma unroll
                for (int i = 0; i < 4; ++i) {
                    const float s = (&sv4[i].x)[mm];
#pragma unroll
                    for (int j = 0; j < 4; ++j)
                        O[i][j] = fmaf(s, vv[j], O[i][j]);
                }
            }
        }
    }

    // write output
#pragma unroll
    for (int i = 0; i < 4; ++i) {
        const long long r = bbase + n0 + ty + 16 * i;
#pragma unroll
        for (int j = 0; j < 4; ++j)
            Out[r * HD + tx + 16 * j] = O[i][j];
    }
}

// ---------------------------------------------------------------------------
extern "C" void kernel_launch(void* const* d_in, const int* in_sizes, int n_in,
                              void* d_out, int out_size, void* d_ws, size_t ws_size,
                              hipStream_t stream)
{
    const float* X  = (const float*)d_in[0];
    const float* WQ = (const float*)d_in[1];
    const float* WK = (const float*)d_in[2];
    const float* WV = (const float*)d_in[3];
    float* Out = (float*)d_out;

    float* Qw = (float*)d_ws;                       // 3 x 4MB scratch in d_ws
    float* Kw = Qw + (size_t)NBATCH * SEQ * HD;
    float* Vw = Kw + (size_t)NBATCH * SEQ * HD;

    proj_xpos_kernel<<<dim3((NBATCH * SEQ) / 32), 256, 0, stream>>>(
        X, WQ, WK, WV, Qw, Kw, Vw);
    retention_kernel<<<dim3(SEQ / 64, NBATCH), 256, 0, stream>>>(
        Qw, Kw, Vw, Out);
}

// Round 2
// 60.789 us; speedup vs baseline: 4.5725x; 4.5725x over previous
//
#include <hip/hip_runtime.h>
#include <hip/hip_bf16.h>
#include <math.h>

// SimpleRetention on MI355X, round 2: bf16 MFMA retention + xPos table.
// out = (Q K^T ∘ D) V, D[n,m]=gamma^(n-m)[n>=m], gamma=0.96875.
// Banded: gamma^513 ~ 8e-8 -> window of 8 previous 64-tiles + diagonal.

#define SEQ    4096
#define NB     4
#define HID    256
#define HD     64
#define WT     8          // previous tiles in band

typedef short          bf16x8 __attribute__((ext_vector_type(8)));
typedef float          f32x4  __attribute__((ext_vector_type(4)));
typedef unsigned short u16;
typedef unsigned int   u32;
typedef u16            u16x8  __attribute__((ext_vector_type(8)));

__device__ __forceinline__ u16 f2bf(float f) {
    __hip_bfloat16 h = __float2bfloat16(f);
    return __builtin_bit_cast(u16, h);
}
__device__ __forceinline__ float bf2f(u16 b) {
    __hip_bfloat16 h = __builtin_bit_cast(__hip_bfloat16, b);
    return __bfloat162float(h);
}

// ---------------------------------------------------------------------------
// xPos table: per (n, i) -> {cos*s, sin*s, cos/s, sin/s}. 4096x32 float4.
// ---------------------------------------------------------------------------
__global__ __launch_bounds__(256)
void xpos_table_kernel(float* __restrict__ T)
{
    const int p = blockIdx.x * 256 + threadIdx.x;   // 131072 tasks
    const int n = p >> 5, i = p & 31;
    const float sv = (2.f * (float)i + 25.6f) / 89.6f;
    const float sc = powf(sv, (float)n * (1.f / 512.f));
    const float inv_freq = 1.f / powf(10000.f, (float)i * (1.f / 32.f));
    float sn, cs;
    sincosf((float)n * inv_freq, &sn, &cs);
    float4 o;
    o.x = cs * sc; o.y = sn * sc;           // Q (downscale=False)
    o.z = cs / sc; o.w = sn / sc;           // K (downscale=True)
    reinterpret_cast<float4*>(T)[p] = o;
}

// ---------------------------------------------------------------------------
// Projection + xPos: X@{WQ,WK,WV}, rotate Q/K via table, emit bf16 hi/lo.
// Qh/Ql/Kh/Kl packed as u32 (pair 2i,2i+1), V plain bf16.
// ---------------------------------------------------------------------------
__global__ __launch_bounds__(256)
void proj_xpos_kernel(const float* __restrict__ X,
                      const float* __restrict__ WQ,
                      const float* __restrict__ WK,
                      const float* __restrict__ WV,
                      const float* __restrict__ Tbl,
                      u32* __restrict__ Qh, u32* __restrict__ Ql,
                      u32* __restrict__ Kh, u32* __restrict__ Kl,
                      u16* __restrict__ Vb)
{
    __shared__ __align__(16) float Xs[32 * 260];
    const int t = threadIdx.x;
    const long long row0 = (long long)blockIdx.x * 32;

    for (int e = t; e < 32 * 64; e += 256) {
        const int r = e >> 6, k4 = (e & 63) << 2;
        *reinterpret_cast<float4*>(&Xs[r * 260 + k4]) =
            *reinterpret_cast<const float4*>(&X[(row0 + r) * HID + k4]);
    }
    __syncthreads();

    const int ty = t >> 6;   // 0..3
    const int tx = t & 63;
    float accQ[8], accK[8], accV[8];
#pragma unroll
    for (int i = 0; i < 8; ++i) { accQ[i] = 0.f; accK[i] = 0.f; accV[i] = 0.f; }

    for (int k0 = 0; k0 < HID; k0 += 4) {
        float4 xv[8];
#pragma unroll
        for (int i = 0; i < 8; ++i)
            xv[i] = *reinterpret_cast<const float4*>(&Xs[(ty + 4 * i) * 260 + k0]);
#pragma unroll
        for (int kk = 0; kk < 4; ++kk) {
            const float wq = WQ[(k0 + kk) * HD + tx];
            const float wk = WK[(k0 + kk) * HD + tx];
            const float wv = WV[(k0 + kk) * HD + tx];
#pragma unroll
            for (int i = 0; i < 8; ++i) {
                const float x = (&xv[i].x)[kk];
                accQ[i] = fmaf(x, wq, accQ[i]);
                accK[i] = fmaf(x, wk, accK[i]);
                accV[i] = fmaf(x, wv, accV[i]);
            }
        }
    }

#pragma unroll
    for (int i = 0; i < 8; ++i)
        Vb[(row0 + ty + 4 * i) * HD + tx] = f2bf(accV[i]);

    __syncthreads();
    float* Raw = Xs;   // 32 x 130 (Q | K)
#pragma unroll
    for (int i = 0; i < 8; ++i) {
        Raw[(ty + 4 * i) * 130 + tx]      = accQ[i];
        Raw[(ty + 4 * i) * 130 + 64 + tx] = accK[i];
    }
    __syncthreads();

    for (int p = t; p < 32 * 64; p += 256) {
        const int r = p >> 6, c = p & 63;
        const bool isK = (c >= 32);
        const int i = c & 31;
        const int n = (int)((row0 + r) & (SEQ - 1));
        const float4 tb = reinterpret_cast<const float4*>(Tbl)[n * 32 + i];
        const float cs = isK ? tb.z : tb.x;
        const float sn = isK ? tb.w : tb.y;
        const int base = isK ? 64 : 0;
        const float x1 = Raw[r * 130 + base + 2 * i];
        const float x2 = Raw[r * 130 + base + 2 * i + 1];
        const float o1 = x1 * cs - x2 * sn;
        const float o2 = x2 * cs + x1 * sn;
        const u16 h1 = f2bf(o1);
        const u16 h2 = f2bf(o2);
        const u16 l1 = f2bf(o1 - bf2f(h1));
        const u16 l2 = f2bf(o2 - bf2f(h2));
        const long long idx = (row0 + r) * 32 + i;
        if (isK) { Kh[idx] = (u32)h1 | ((u32)h2 << 16); Kl[idx] = (u32)l1 | ((u32)l2 << 16); }
        else     { Qh[idx] = (u32)h1 | ((u32)h2 << 16); Ql[idx] = (u32)l1 | ((u32)l2 << 16); }
    }
}

// ---------------------------------------------------------------------------
// Banded retention, bf16 MFMA. grid (64 n-tiles, 4 batches), 512 threads.
// Q/K split hi/lo (3-term products); S, V plain bf16.
// ---------------------------------------------------------------------------
#define LDSW 80   // bf16 row stride: 160 B (16B-aligned, 8-word bank stride)

__global__ __launch_bounds__(512)
void retention_kernel(const u32* __restrict__ Qh, const u32* __restrict__ Ql,
                      const u32* __restrict__ Kh, const u32* __restrict__ Kl,
                      const u16* __restrict__ Vb, float* __restrict__ Out)
{
    __shared__ __align__(16) u16 Qhs[64 * LDSW];
    __shared__ __align__(16) u16 Qls[64 * LDSW];
    __shared__ __align__(16) u16 Khs[64 * LDSW];
    __shared__ __align__(16) u16 Kls[64 * LDSW];
    __shared__ __align__(16) u16 Ss [64 * LDSW];
    __shared__ __align__(16) u16 Vts[64 * LDSW];   // V transposed: [v][m]

    const int t    = threadIdx.x;
    const int lane = t & 63;
    const int w    = t >> 6;       // wave 0..7
    const int rb   = w >> 1;       // row block 0..3 (16 rows each)
    const int cb   = w & 1;        // col block 0..1 (32 cols each)
    const int nt   = blockIdx.x;
    const int b    = blockIdx.y;
    const int n0   = nt * 64;
    const long long bbase = (long long)b * SEQ;

    const int srow = t >> 3;           // staging: row 0..63
    const int scol = (t & 7) * 8;      // staging: col8

    const u16* Qh16 = (const u16*)Qh;
    const u16* Ql16 = (const u16*)Ql;
    const u16* Kh16 = (const u16*)Kh;
    const u16* Kl16 = (const u16*)Kl;

    // stage Q (hi/lo)
    *reinterpret_cast<u16x8*>(&Qhs[srow * LDSW + scol]) =
        *reinterpret_cast<const u16x8*>(&Qh16[(bbase + n0 + srow) * HD + scol]);
    *reinterpret_cast<u16x8*>(&Qls[srow * LDSW + scol]) =
        *reinterpret_cast<const u16x8*>(&Ql16[(bbase + n0 + srow) * HD + scol]);
    __syncthreads();

    // hoisted Q fragments: row = rb*16 + (lane&15), k-chunks 0 / 32
    const int frow = rb * 16 + (lane & 15);
    const int fk   = (lane >> 4) * 8;
    const bf16x8 qh0 = *reinterpret_cast<const bf16x8*>(&Qhs[frow * LDSW + fk]);
    const bf16x8 qh1 = *reinterpret_cast<const bf16x8*>(&Qhs[frow * LDSW + 32 + fk]);
    const bf16x8 ql0 = *reinterpret_cast<const bf16x8*>(&Qls[frow * LDSW + fk]);
    const bf16x8 ql1 = *reinterpret_cast<const bf16x8*>(&Qls[frow * LDSW + 32 + fk]);

    f32x4 accO[2];
    accO[0] = (f32x4)0.f; accO[1] = (f32x4)0.f;

    const float log2g = -0.04580368544f;   // log2(0.96875)
    const int mt0 = (nt >= WT) ? (nt - WT) : 0;

    for (int mt = mt0; mt <= nt; ++mt) {
        const int m0 = mt * 64;
        __syncthreads();   // B1: previous SV done with Khs/Kls/Vts/Ss

        // stage K hi/lo (row-major) and V (transposed)
        *reinterpret_cast<u16x8*>(&Khs[srow * LDSW + scol]) =
            *reinterpret_cast<const u16x8*>(&Kh16[(bbase + m0 + srow) * HD + scol]);
        *reinterpret_cast<u16x8*>(&Kls[srow * LDSW + scol]) =
            *reinterpret_cast<const u16x8*>(&Kl16[(bbase + m0 + srow) * HD + scol]);
        {
            const u16x8 vv = *reinterpret_cast<const u16x8*>(&Vb[(bbase + m0 + srow) * HD + scol]);
#pragma unroll
            for (int j = 0; j < 8; ++j)
                Vts[(scol + j) * LDSW + srow] = vv[j];
        }
        __syncthreads();   // B2: tiles staged

        // ---- S = Q K^T (hi/lo split, 3-term) ----
        f32x4 accS[2];
        accS[0] = (f32x4)0.f; accS[1] = (f32x4)0.f;
#pragma unroll
        for (int ms = 0; ms < 2; ++ms) {
            const int mrow = (cb * 2 + ms) * 16 + (lane & 15);
            const bf16x8 kh0 = *reinterpret_cast<const bf16x8*>(&Khs[mrow * LDSW + fk]);
            const bf16x8 kh1 = *reinterpret_cast<const bf16x8*>(&Khs[mrow * LDSW + 32 + fk]);
            const bf16x8 kl0 = *reinterpret_cast<const bf16x8*>(&Kls[mrow * LDSW + fk]);
            const bf16x8 kl1 = *reinterpret_cast<const bf16x8*>(&Kls[mrow * LDSW + 32 + fk]);
            accS[ms] = __builtin_amdgcn_mfma_f32_16x16x32_bf16(qh0, kh0, accS[ms], 0, 0, 0);
            accS[ms] = __builtin_amdgcn_mfma_f32_16x16x32_bf16(qh1, kh1, accS[ms], 0, 0, 0);
            accS[ms] = __builtin_amdgcn_mfma_f32_16x16x32_bf16(ql0, kh0, accS[ms], 0, 0, 0);
            accS[ms] = __builtin_amdgcn_mfma_f32_16x16x32_bf16(ql1, kh1, accS[ms], 0, 0, 0);
            accS[ms] = __builtin_amdgcn_mfma_f32_16x16x32_bf16(qh0, kl0, accS[ms], 0, 0, 0);
            accS[ms] = __builtin_amdgcn_mfma_f32_16x16x32_bf16(qh1, kl1, accS[ms], 0, 0, 0);
        }

        // ---- decay + mask + bf16, write S to LDS ----
#pragma unroll
        for (int ms = 0; ms < 2; ++ms) {
            const int mloc = (cb * 2 + ms) * 16 + (lane & 15);
            const int dm   = (n0 - m0) - mloc;
#pragma unroll
            for (int reg = 0; reg < 4; ++reg) {
                const int nloc = rb * 16 + (lane >> 4) * 4 + reg;
                const int d    = dm + nloc;
                const float g  = (d >= 0) ? exp2f((float)d * log2g) : 0.f;
                Ss[nloc * LDSW + mloc] = f2bf(accS[ms][reg] * g);
            }
        }
        __syncthreads();   // B3: S ready

        // ---- O += S V ----
        const bf16x8 s0 = *reinterpret_cast<const bf16x8*>(&Ss[frow * LDSW + fk]);
        const bf16x8 s1 = *reinterpret_cast<const bf16x8*>(&Ss[frow * LDSW + 32 + fk]);
#pragma unroll
        for (int vv = 0; vv < 2; ++vv) {
            const int vrow = cb * 32 + vv * 16 + (lane & 15);
            const bf16x8 v0 = *reinterpret_cast<const bf16x8*>(&Vts[vrow * LDSW + fk]);
            const bf16x8 v1 = *reinterpret_cast<const bf16x8*>(&Vts[vrow * LDSW + 32 + fk]);
            accO[vv] = __builtin_amdgcn_mfma_f32_16x16x32_bf16(s0, v0, accO[vv], 0, 0, 0);
            accO[vv] = __builtin_amdgcn_mfma_f32_16x16x32_bf16(s1, v1, accO[vv], 0, 0, 0);
        }
    }

    // write output (fp32)
#pragma unroll
    for (int vv = 0; vv < 2; ++vv) {
        const int v = cb * 32 + vv * 16 + (lane & 15);
#pragma unroll
        for (int reg = 0; reg < 4; ++reg) {
            const int n = n0 + rb * 16 + (lane >> 4) * 4 + reg;
            Out[(bbase + n) * HD + v] = accO[vv][reg];
        }
    }
}

// ---------------------------------------------------------------------------
extern "C" void kernel_launch(void* const* d_in, const int* in_sizes, int n_in,
                              void* d_out, int out_size, void* d_ws, size_t ws_size,
                              hipStream_t stream)
{
    const float* X  = (const float*)d_in[0];
    const float* WQ = (const float*)d_in[1];
    const float* WK = (const float*)d_in[2];
    const float* WV = (const float*)d_in[3];
    float* Out = (float*)d_out;

    char* ws = (char*)d_ws;
    const size_t QK_BYTES = (size_t)NB * SEQ * 32 * sizeof(u32);   // 2 MB
    u32* Qh = (u32*)(ws);
    u32* Ql = (u32*)(ws + QK_BYTES);
    u32* Kh = (u32*)(ws + 2 * QK_BYTES);
    u32* Kl = (u32*)(ws + 3 * QK_BYTES);
    u16* Vb = (u16*)(ws + 4 * QK_BYTES);                           // 2 MB
    float* Tbl = (float*)(ws + 5 * QK_BYTES);                      // 2 MB

    xpos_table_kernel<<<dim3(SEQ * 32 / 256), 256, 0, stream>>>(Tbl);
    proj_xpos_kernel<<<dim3((NB * SEQ) / 32), 256, 0, stream>>>(
        X, WQ, WK, WV, Tbl, Qh, Ql, Kh, Kl, Vb);
    retention_kernel<<<dim3(SEQ / 64, NB), 512, 0, stream>>>(
        Qh, Ql, Kh, Kl, Vb, Out);
}

// Round 3
// 54.831 us; speedup vs baseline: 5.0693x; 1.1087x over previous
//
#include <hip/hip_runtime.h>
#include <hip/hip_bf16.h>
#include <math.h>

// SimpleRetention on MI355X, round 3: MFMA everywhere.
// out = (Q K^T ∘ D) V, D[n,m]=gamma^(n-m)[n>=m], gamma=0.96875.
// Banded: gamma^513 ~ 8e-8 -> window of 8 previous 64-tiles + diagonal.
// Projection: X@{WQ|WK|WV} as bf16 hi/lo 3-term MFMA (fp32-level accuracy),
// W pre-swizzled into MFMA B-fragment order, xPos rotation fused post-MFMA.

#define SEQ    4096
#define NB     4
#define HID    256
#define HD     64
#define WT     8          // previous tiles in band

typedef short          bf16x8 __attribute__((ext_vector_type(8)));
typedef float          f32x4  __attribute__((ext_vector_type(4)));
typedef unsigned short u16;
typedef u16            u16x8  __attribute__((ext_vector_type(8)));
typedef u16            u16x4  __attribute__((ext_vector_type(4)));

__device__ __forceinline__ u16 f2bf(float f) {
    __hip_bfloat16 h = __float2bfloat16(f);
    return __builtin_bit_cast(u16, h);
}
__device__ __forceinline__ float bf2f(u16 b) {
    __hip_bfloat16 h = __builtin_bit_cast(__hip_bfloat16, b);
    return __bfloat162float(h);
}

// ---------------------------------------------------------------------------
// Prep: xPos table (blocks 0..511) + W fragment swizzle hi/lo (blocks 512..535).
// Wf layout: frag f = ((ct*8 + kc)*64 + lane), 8 contiguous bf16:
//   b[j] = W[kc*32 + (lane>>4)*8 + j][ct*16 + (lane&15)]  (cols: Q|K|V).
// ---------------------------------------------------------------------------
__global__ __launch_bounds__(256)
void prep_kernel(const float* __restrict__ WQ, const float* __restrict__ WK,
                 const float* __restrict__ WV, float* __restrict__ Tbl,
                 u16* __restrict__ Wfh, u16* __restrict__ Wfl)
{
    const int t = threadIdx.x;
    if (blockIdx.x < 512) {
        const int p = blockIdx.x * 256 + t;          // 131072 (n,i) tasks
        const int n = p >> 5, i = p & 31;
        const float sv = (2.f * (float)i + 25.6f) / 89.6f;
        const float sc = powf(sv, (float)n * (1.f / 512.f));
        const float inv_freq = 1.f / powf(10000.f, (float)i * (1.f / 32.f));
        float sn, cs;
        sincosf((float)n * inv_freq, &sn, &cs);
        float4 o;
        o.x = cs * sc; o.y = sn * sc;                // Q (downscale=False)
        o.z = cs / sc; o.w = sn / sc;                // K (downscale=True)
        reinterpret_cast<float4*>(Tbl)[p] = o;
    } else {
        const int p = (blockIdx.x - 512) * 256 + t;  // 0..6143
        const int lane = p & 63;
        const int kc   = (p >> 6) & 7;
        const int ct   = p >> 9;                     // 0..11
        const int col  = ct * 16 + (lane & 15);
        const float* Wsrc = (col < 64) ? WQ : (col < 128) ? WK : WV;
        const int c = col & 63;
        u16x8 hv, lv;
#pragma unroll
        for (int j = 0; j < 8; ++j) {
            const float w = Wsrc[(kc * 32 + (lane >> 4) * 8 + j) * HD + c];
            hv[j] = f2bf(w);
            lv[j] = f2bf(w - bf2f(hv[j]));
        }
        *reinterpret_cast<u16x8*>(&Wfh[(size_t)p * 8]) = hv;
        *reinterpret_cast<u16x8*>(&Wfl[(size_t)p * 8]) = lv;
    }
}

// ---------------------------------------------------------------------------
// Projection + fused xPos, MFMA. 512 blocks x 256 thr, 32 rows/block.
// ---------------------------------------------------------------------------
#define XLDS 264   // bf16 row stride: 528 B -> 4-bank shift/row, 2-way alias (free)

__device__ __forceinline__ void emit_tile(int ct, f32x4 acc, long long grow0, int lane,
                                          const float* __restrict__ Tbl,
                                          u16* __restrict__ Qh, u16* __restrict__ Ql,
                                          u16* __restrict__ Kh, u16* __restrict__ Kl,
                                          u16* __restrict__ Vb)
{
    const int c16   = lane & 15;
    const int rbase = (lane >> 4) * 4;
    if (ct < 8) {
        const bool isK = ct >= 4;
        const int cq  = (ct & 3) * 16 + c16;
        const int i   = cq >> 1;
        const int odd = cq & 1;
        u16* Ph = isK ? Kh : Qh;
        u16* Pl = isK ? Kl : Ql;
#pragma unroll
        for (int reg = 0; reg < 4; ++reg) {
            const long long r = grow0 + rbase + reg;
            const int n = (int)(r & (SEQ - 1));
            const float4 tb = reinterpret_cast<const float4*>(Tbl)[n * 32 + i];
            const float cs = isK ? tb.z : tb.x;
            const float sn = isK ? tb.w : tb.y;
            const float x  = acc[reg];
            const float xp = __shfl_xor(x, 1, 64);   // partner column value
            const float o  = odd ? fmaf(x, cs, xp * sn) : fmaf(x, cs, -xp * sn);
            const u16 h = f2bf(o);
            Ph[r * HD + cq] = h;
            Pl[r * HD + cq] = f2bf(o - bf2f(h));
        }
    } else {
        const int cv = (ct - 8) * 16 + c16;
#pragma unroll
        for (int reg = 0; reg < 4; ++reg) {
            const long long r = grow0 + rbase + reg;
            Vb[r * HD + cv] = f2bf(acc[reg]);
        }
    }
}

__global__ __launch_bounds__(256, 2)
void proj_kernel(const float* __restrict__ X, const float* __restrict__ Tbl,
                 const u16* __restrict__ Wfh, const u16* __restrict__ Wfl,
                 u16* __restrict__ Qh, u16* __restrict__ Ql,
                 u16* __restrict__ Kh, u16* __restrict__ Kl,
                 u16* __restrict__ Vb)
{
    __shared__ __align__(16) u16 Xhs[32 * XLDS];
    __shared__ __align__(16) u16 Xls[32 * XLDS];
    const int t = threadIdx.x;
    const long long row0 = (long long)blockIdx.x * 32;

    // stage X tile as bf16 hi/lo
    for (int e = t; e < 32 * 64; e += 256) {
        const int r = e >> 6, k4 = (e & 63) << 2;
        const float4 xv = *reinterpret_cast<const float4*>(&X[(row0 + r) * HID + k4]);
        u16x4 hv, lv;
#pragma unroll
        for (int j = 0; j < 4; ++j) {
            const float f = (&xv.x)[j];
            hv[j] = f2bf(f);
            lv[j] = f2bf(f - bf2f(hv[j]));
        }
        *reinterpret_cast<u16x4*>(&Xhs[r * XLDS + k4]) = hv;
        *reinterpret_cast<u16x4*>(&Xls[r * XLDS + k4]) = lv;
    }
    __syncthreads();

    const int lane = t & 63;
    const int w    = t >> 6;
    const int rt   = w >> 1;      // row-tile 0..1 (16 rows)
    const int ch   = w & 1;       // col-half: 6 col-tiles each
    const int frow = rt * 16 + (lane & 15);
    const int fk   = (lane >> 4) * 8;

    // hoist all A-fragments (hi/lo per k-chunk)
    bf16x8 ah[8], al[8];
#pragma unroll
    for (int kc = 0; kc < 8; ++kc) {
        ah[kc] = *reinterpret_cast<const bf16x8*>(&Xhs[frow * XLDS + kc * 32 + fk]);
        al[kc] = *reinterpret_cast<const bf16x8*>(&Xls[frow * XLDS + kc * 32 + fk]);
    }

    const long long grow0 = row0 + rt * 16;

    for (int ctp = 0; ctp < 3; ++ctp) {
        const int ct0 = ch * 6 + ctp * 2;
        f32x4 acc0 = (f32x4)0.f, acc1 = (f32x4)0.f;
#pragma unroll
        for (int kc = 0; kc < 8; ++kc) {
            const size_t f0 = (size_t)((ct0 * 8 + kc) * 64 + lane) * 8;
            const size_t f1 = (size_t)(((ct0 + 1) * 8 + kc) * 64 + lane) * 8;
            const bf16x8 bh0 = *reinterpret_cast<const bf16x8*>(&Wfh[f0]);
            const bf16x8 bl0 = *reinterpret_cast<const bf16x8*>(&Wfl[f0]);
            const bf16x8 bh1 = *reinterpret_cast<const bf16x8*>(&Wfh[f1]);
            const bf16x8 bl1 = *reinterpret_cast<const bf16x8*>(&Wfl[f1]);
            acc0 = __builtin_amdgcn_mfma_f32_16x16x32_bf16(ah[kc], bh0, acc0, 0, 0, 0);
            acc1 = __builtin_amdgcn_mfma_f32_16x16x32_bf16(ah[kc], bh1, acc1, 0, 0, 0);
            acc0 = __builtin_amdgcn_mfma_f32_16x16x32_bf16(al[kc], bh0, acc0, 0, 0, 0);
            acc1 = __builtin_amdgcn_mfma_f32_16x16x32_bf16(al[kc], bh1, acc1, 0, 0, 0);
            acc0 = __builtin_amdgcn_mfma_f32_16x16x32_bf16(ah[kc], bl0, acc0, 0, 0, 0);
            acc1 = __builtin_amdgcn_mfma_f32_16x16x32_bf16(ah[kc], bl1, acc1, 0, 0, 0);
        }
        emit_tile(ct0,     acc0, grow0, lane, Tbl, Qh, Ql, Kh, Kl, Vb);
        emit_tile(ct0 + 1, acc1, grow0, lane, Tbl, Qh, Ql, Kh, Kl, Vb);
    }
}

// ---------------------------------------------------------------------------
// Banded retention, bf16 MFMA. grid (64 n-tiles, 4 batches), 512 threads.
// ---------------------------------------------------------------------------
#define LDSW 80   // bf16 row stride: 160 B

__global__ __launch_bounds__(512)
void retention_kernel(const u16* __restrict__ Qh16, const u16* __restrict__ Ql16,
                      const u16* __restrict__ Kh16, const u16* __restrict__ Kl16,
                      const u16* __restrict__ Vb, float* __restrict__ Out)
{
    __shared__ __align__(16) u16 Qhs[64 * LDSW];
    __shared__ __align__(16) u16 Qls[64 * LDSW];
    __shared__ __align__(16) u16 Khs[64 * LDSW];
    __shared__ __align__(16) u16 Kls[64 * LDSW];
    __shared__ __align__(16) u16 Ss [64 * LDSW];
    __shared__ __align__(16) u16 Vts[64 * LDSW];   // V transposed: [v][m]

    const int t    = threadIdx.x;
    const int lane = t & 63;
    const int w    = t >> 6;
    const int rb   = w >> 1;       // row block 0..3
    const int cb   = w & 1;        // col block 0..1
    const int nt   = blockIdx.x;
    const int b    = blockIdx.y;
    const int n0   = nt * 64;
    const long long bbase = (long long)b * SEQ;

    const int srow = t >> 3;
    const int scol = (t & 7) * 8;

    *reinterpret_cast<u16x8*>(&Qhs[srow * LDSW + scol]) =
        *reinterpret_cast<const u16x8*>(&Qh16[(bbase + n0 + srow) * HD + scol]);
    *reinterpret_cast<u16x8*>(&Qls[srow * LDSW + scol]) =
        *reinterpret_cast<const u16x8*>(&Ql16[(bbase + n0 + srow) * HD + scol]);
    __syncthreads();

    const int frow = rb * 16 + (lane & 15);
    const int fk   = (lane >> 4) * 8;
    const bf16x8 qh0 = *reinterpret_cast<const bf16x8*>(&Qhs[frow * LDSW + fk]);
    const bf16x8 qh1 = *reinterpret_cast<const bf16x8*>(&Qhs[frow * LDSW + 32 + fk]);
    const bf16x8 ql0 = *reinterpret_cast<const bf16x8*>(&Qls[frow * LDSW + fk]);
    const bf16x8 ql1 = *reinterpret_cast<const bf16x8*>(&Qls[frow * LDSW + 32 + fk]);

    f32x4 accO[2];
    accO[0] = (f32x4)0.f; accO[1] = (f32x4)0.f;

    const float log2g = -0.04580368544f;   // log2(0.96875)
    const int mt0 = (nt >= WT) ? (nt - WT) : 0;

    for (int mt = mt0; mt <= nt; ++mt) {
        const int m0 = mt * 64;
        __syncthreads();

        *reinterpret_cast<u16x8*>(&Khs[srow * LDSW + scol]) =
            *reinterpret_cast<const u16x8*>(&Kh16[(bbase + m0 + srow) * HD + scol]);
        *reinterpret_cast<u16x8*>(&Kls[srow * LDSW + scol]) =
            *reinterpret_cast<const u16x8*>(&Kl16[(bbase + m0 + srow) * HD + scol]);
        {
            const u16x8 vv = *reinterpret_cast<const u16x8*>(&Vb[(bbase + m0 + srow) * HD + scol]);
#pragma unroll
            for (int j = 0; j < 8; ++j)
                Vts[(scol + j) * LDSW + srow] = vv[j];
        }
        __syncthreads();

        // ---- S = Q K^T (hi/lo 3-term) ----
        f32x4 accS[2];
        accS[0] = (f32x4)0.f; accS[1] = (f32x4)0.f;
#pragma unroll
        for (int ms = 0; ms < 2; ++ms) {
            const int mrow = (cb * 2 + ms) * 16 + (lane & 15);
            const bf16x8 kh0 = *reinterpret_cast<const bf16x8*>(&Khs[mrow * LDSW + fk]);
            const bf16x8 kh1 = *reinterpret_cast<const bf16x8*>(&Khs[mrow * LDSW + 32 + fk]);
            const bf16x8 kl0 = *reinterpret_cast<const bf16x8*>(&Kls[mrow * LDSW + fk]);
            const bf16x8 kl1 = *reinterpret_cast<const bf16x8*>(&Kls[mrow * LDSW + 32 + fk]);
            accS[ms] = __builtin_amdgcn_mfma_f32_16x16x32_bf16(qh0, kh0, accS[ms], 0, 0, 0);
            accS[ms] = __builtin_amdgcn_mfma_f32_16x16x32_bf16(qh1, kh1, accS[ms], 0, 0, 0);
            accS[ms] = __builtin_amdgcn_mfma_f32_16x16x32_bf16(ql0, kh0, accS[ms], 0, 0, 0);
            accS[ms] = __builtin_amdgcn_mfma_f32_16x16x32_bf16(ql1, kh1, accS[ms], 0, 0, 0);
            accS[ms] = __builtin_amdgcn_mfma_f32_16x16x32_bf16(qh0, kl0, accS[ms], 0, 0, 0);
            accS[ms] = __builtin_amdgcn_mfma_f32_16x16x32_bf16(qh1, kl1, accS[ms], 0, 0, 0);
        }

        // ---- decay + mask + bf16, stage S ----
#pragma unroll
        for (int ms = 0; ms < 2; ++ms) {
            const int mloc = (cb * 2 + ms) * 16 + (lane & 15);
            const int dm   = (n0 - m0) - mloc;
#pragma unroll
            for (int reg = 0; reg < 4; ++reg) {
                const int nloc = rb * 16 + (lane >> 4) * 4 + reg;
                const int d    = dm + nloc;
                const float g  = (d >= 0) ? exp2f((float)d * log2g) : 0.f;
                Ss[nloc * LDSW + mloc] = f2bf(accS[ms][reg] * g);
            }
        }
        __syncthreads();

        // ---- O += S V ----
        const bf16x8 s0 = *reinterpret_cast<const bf16x8*>(&Ss[frow * LDSW + fk]);
        const bf16x8 s1 = *reinterpret_cast<const bf16x8*>(&Ss[frow * LDSW + 32 + fk]);
#pragma unroll
        for (int vv = 0; vv < 2; ++vv) {
            const int vrow = cb * 32 + vv * 16 + (lane & 15);
            const bf16x8 v0 = *reinterpret_cast<const bf16x8*>(&Vts[vrow * LDSW + fk]);
            const bf16x8 v1 = *reinterpret_cast<const bf16x8*>(&Vts[vrow * LDSW + 32 + fk]);
            accO[vv] = __builtin_amdgcn_mfma_f32_16x16x32_bf16(s0, v0, accO[vv], 0, 0, 0);
            accO[vv] = __builtin_amdgcn_mfma_f32_16x16x32_bf16(s1, v1, accO[vv], 0, 0, 0);
        }
    }

#pragma unroll
    for (int vv = 0; vv < 2; ++vv) {
        const int v = cb * 32 + vv * 16 + (lane & 15);
#pragma unroll
        for (int reg = 0; reg < 4; ++reg) {
            const int n = n0 + rb * 16 + (lane >> 4) * 4 + reg;
            Out[(bbase + n) * HD + v] = accO[vv][reg];
        }
    }
}

// ---------------------------------------------------------------------------
extern "C" void kernel_launch(void* const* d_in, const int* in_sizes, int n_in,
                              void* d_out, int out_size, void* d_ws, size_t ws_size,
                              hipStream_t stream)
{
    const float* X  = (const float*)d_in[0];
    const float* WQ = (const float*)d_in[1];
    const float* WK = (const float*)d_in[2];
    const float* WV = (const float*)d_in[3];
    float* Out = (float*)d_out;

    char* ws = (char*)d_ws;
    const size_t SZ = (size_t)NB * SEQ * HD * sizeof(u16);   // 2 MB
    u16* Qh = (u16*)(ws);
    u16* Ql = (u16*)(ws + SZ);
    u16* Kh = (u16*)(ws + 2 * SZ);
    u16* Kl = (u16*)(ws + 3 * SZ);
    u16* Vb = (u16*)(ws + 4 * SZ);
    float* Tbl = (float*)(ws + 5 * SZ);                      // 2 MB
    u16* Wfh = (u16*)(ws + 6 * SZ);                          // 96 KB (pad 128K)
    u16* Wfl = (u16*)(ws + 6 * SZ + (128 << 10));

    prep_kernel<<<dim3(536), 256, 0, stream>>>(WQ, WK, WV, Tbl, Wfh, Wfl);
    proj_kernel<<<dim3((NB * SEQ) / 32), 256, 0, stream>>>(
        X, Tbl, Wfh, Wfl, Qh, Ql, Kh, Kl, Vb);
    retention_kernel<<<dim3(SEQ / 64, NB), 512, 0, stream>>>(
        Qh, Ql, Kh, Kl, Vb, Out);
}

// Round 4
// 42.379 us; speedup vs baseline: 6.5589x; 1.2938x over previous
//
#include <hip/hip_runtime.h>
#include <hip/hip_bf16.h>
#include <math.h>

// SimpleRetention on MI355X, round 4.
// out = (Q K^T ∘ D) V, D[n,m]=gamma^(n-m)[n>=m], gamma=0.96875.
// Banded: gamma^513 ~ 8e-8 -> window of 8 previous 64-tiles + diagonal.
// proj v3: kc-outer MFMA (L1-resident W slices), no LDS.
// retention v2: chunk-XOR V-transpose (conflict-free), stride-68 S,
//               K/V double-buffer prefetch, 2 barriers/tile.

#define SEQ    4096
#define NB     4
#define HID    256
#define HD     64
#define WT     8

typedef short          bf16x8 __attribute__((ext_vector_type(8)));
typedef float          f32x4  __attribute__((ext_vector_type(4)));
typedef unsigned short u16;
typedef unsigned int   u32;
typedef u16            u16x8  __attribute__((ext_vector_type(8)));
typedef u16            u16x4  __attribute__((ext_vector_type(4)));

__device__ __forceinline__ u16 f2bf(float f) {
    __hip_bfloat16 h = __float2bfloat16(f);
    return __builtin_bit_cast(u16, h);
}
__device__ __forceinline__ float bf2f(u16 b) {
    __hip_bfloat16 h = __builtin_bit_cast(__hip_bfloat16, b);
    return __bfloat162float(h);
}

// ---------------------------------------------------------------------------
// Prep: xPos table (blocks 0..511) + W fragment swizzle hi/lo (blocks 512..535).
// Wf frag f = ((ct*8 + kc)*64 + lane): b[j] = W[kc*32+(lane>>4)*8+j][ct*16+(lane&15)]
// ---------------------------------------------------------------------------
__global__ __launch_bounds__(256)
void prep_kernel(const float* __restrict__ WQ, const float* __restrict__ WK,
                 const float* __restrict__ WV, float* __restrict__ Tbl,
                 u16* __restrict__ Wfh, u16* __restrict__ Wfl)
{
    const int t = threadIdx.x;
    if (blockIdx.x < 512) {
        const int p = blockIdx.x * 256 + t;
        const int n = p >> 5, i = p & 31;
        const float sv = (2.f * (float)i + 25.6f) / 89.6f;
        const float sc = powf(sv, (float)n * (1.f / 512.f));
        const float inv_freq = 1.f / powf(10000.f, (float)i * (1.f / 32.f));
        float sn, cs;
        sincosf((float)n * inv_freq, &sn, &cs);
        float4 o;
        o.x = cs * sc; o.y = sn * sc;   // Q (downscale=False)
        o.z = cs / sc; o.w = sn / sc;   // K (downscale=True)
        reinterpret_cast<float4*>(Tbl)[p] = o;
    } else {
        const int p = (blockIdx.x - 512) * 256 + t;   // 0..6143
        const int lane = p & 63;
        const int kc   = (p >> 6) & 7;
        const int ct   = p >> 9;                      // 0..11
        const int col  = ct * 16 + (lane & 15);
        const float* Wsrc = (col < 64) ? WQ : (col < 128) ? WK : WV;
        const int c = col & 63;
        u16x8 hv, lv;
#pragma unroll
        for (int j = 0; j < 8; ++j) {
            const float w = Wsrc[(kc * 32 + (lane >> 4) * 8 + j) * HD + c];
            hv[j] = f2bf(w);
            lv[j] = f2bf(w - bf2f(hv[j]));
        }
        *reinterpret_cast<u16x8*>(&Wfh[(size_t)p * 8]) = hv;
        *reinterpret_cast<u16x8*>(&Wfl[(size_t)p * 8]) = lv;
    }
}

// ---------------------------------------------------------------------------
// Projection + fused xPos. 256 blocks x 512 thr, 64 rows/block, no LDS.
// ---------------------------------------------------------------------------
__device__ __forceinline__ void emit_tile(int ct, f32x4 acc, long long grow0, int lane,
                                          const float* __restrict__ Tbl,
                                          u16* __restrict__ Qh, u16* __restrict__ Ql,
                                          u16* __restrict__ Kh, u16* __restrict__ Kl,
                                          u16* __restrict__ Vb)
{
    const int c16   = lane & 15;
    const int rbase = (lane >> 4) * 4;
    if (ct < 8) {
        const bool isK = ct >= 4;
        const int cq  = (ct & 3) * 16 + c16;
        const int i   = cq >> 1;
        const int odd = cq & 1;
        u16* Ph = isK ? Kh : Qh;
        u16* Pl = isK ? Kl : Ql;
#pragma unroll
        for (int reg = 0; reg < 4; ++reg) {
            const long long r = grow0 + rbase + reg;
            const int n = (int)(r & (SEQ - 1));
            const float4 tb = reinterpret_cast<const float4*>(Tbl)[n * 32 + i];
            const float cs = isK ? tb.z : tb.x;
            const float sn = isK ? tb.w : tb.y;
            const float x  = acc[reg];
            const float xp = __shfl_xor(x, 1, 64);
            const float o  = odd ? fmaf(x, cs, xp * sn) : fmaf(x, cs, -xp * sn);
            const u16 h = f2bf(o);
            Ph[r * HD + cq] = h;
            Pl[r * HD + cq] = f2bf(o - bf2f(h));
        }
    } else {
        const int cv = (ct - 8) * 16 + c16;
#pragma unroll
        for (int reg = 0; reg < 4; ++reg) {
            const long long r = grow0 + rbase + reg;
            Vb[r * HD + cv] = f2bf(acc[reg]);
        }
    }
}

__global__ __launch_bounds__(512, 1)
void proj_kernel(const float* __restrict__ X, const float* __restrict__ Tbl,
                 const u16* __restrict__ Wfh, const u16* __restrict__ Wfl,
                 u16* __restrict__ Qh, u16* __restrict__ Ql,
                 u16* __restrict__ Kh, u16* __restrict__ Kl,
                 u16* __restrict__ Vb)
{
    const int t    = threadIdx.x;
    const int lane = t & 63;
    const int w    = t >> 6;
    const int rt2  = w >> 2;    // 0..1 : 32-row half
    const int ch   = w & 3;     // 0..3 : 3 col-tiles each
    const long long row0 = (long long)blockIdx.x * 64;

    f32x4 acc[2][3];
#pragma unroll
    for (int a = 0; a < 2; ++a)
#pragma unroll
        for (int b = 0; b < 3; ++b) acc[a][b] = (f32x4)0.f;

    for (int kc = 0; kc < 8; ++kc) {
        bf16x8 ah[2], al[2];
#pragma unroll
        for (int rt = 0; rt < 2; ++rt) {
            const long long gr = row0 + rt2 * 32 + rt * 16 + (lane & 15);
            const float* xp = &X[gr * HID + kc * 32 + (lane >> 4) * 8];
            const float4 x0 = *reinterpret_cast<const float4*>(xp);
            const float4 x1 = *reinterpret_cast<const float4*>(xp + 4);
#pragma unroll
            for (int j = 0; j < 4; ++j) {
                const float f0 = (&x0.x)[j];
                const float f1 = (&x1.x)[j];
                const u16 h0 = f2bf(f0), h1 = f2bf(f1);
                ah[rt][j]     = (short)h0;
                ah[rt][4 + j] = (short)h1;
                al[rt][j]     = (short)f2bf(f0 - bf2f(h0));
                al[rt][4 + j] = (short)f2bf(f1 - bf2f(h1));
            }
        }
#pragma unroll
        for (int ctp = 0; ctp < 3; ++ctp) {
            const int ct = ch * 3 + ctp;
            const size_t fb = (size_t)((ct * 8 + kc) * 64 + lane) * 8;
            const bf16x8 wh = *reinterpret_cast<const bf16x8*>(&Wfh[fb]);
            const bf16x8 wl = *reinterpret_cast<const bf16x8*>(&Wfl[fb]);
#pragma unroll
            for (int rt = 0; rt < 2; ++rt) {
                acc[rt][ctp] = __builtin_amdgcn_mfma_f32_16x16x32_bf16(ah[rt], wh, acc[rt][ctp], 0, 0, 0);
                acc[rt][ctp] = __builtin_amdgcn_mfma_f32_16x16x32_bf16(al[rt], wh, acc[rt][ctp], 0, 0, 0);
                acc[rt][ctp] = __builtin_amdgcn_mfma_f32_16x16x32_bf16(ah[rt], wl, acc[rt][ctp], 0, 0, 0);
            }
        }
    }

#pragma unroll
    for (int rt = 0; rt < 2; ++rt) {
        const long long grow0 = row0 + rt2 * 32 + rt * 16;
#pragma unroll
        for (int ctp = 0; ctp < 3; ++ctp)
            emit_tile(ch * 3 + ctp, acc[rt][ctp], grow0, lane, Tbl, Qh, Ql, Kh, Kl, Vb);
    }
}

// ---------------------------------------------------------------------------
// Banded retention. grid (64, 4), 512 thr. K/V dbuf + prefetch, 2 barriers/tile.
// ---------------------------------------------------------------------------
#define KW 80   // K/Q row stride (u16): b128-aligned, conflict-free
#define SW 68   // S row stride: conflict-free scalar writes, b64 reads

__device__ __forceinline__ bf16x8 ld_s8(const u16* p) {
    const u16x4 lo = *reinterpret_cast<const u16x4*>(p);
    const u16x4 hi = *reinterpret_cast<const u16x4*>(p + 4);
    bf16x8 r;
#pragma unroll
    for (int j = 0; j < 4; ++j) { r[j] = (short)lo[j]; r[4 + j] = (short)hi[j]; }
    return r;
}

__global__ __launch_bounds__(512, 1)
void retention_kernel(const u16* __restrict__ Qh16, const u16* __restrict__ Ql16,
                      const u16* __restrict__ Kh16, const u16* __restrict__ Kl16,
                      const u16* __restrict__ Vb, float* __restrict__ Out)
{
    __shared__ __align__(16) u16 Qhs[64 * KW];
    __shared__ __align__(16) u16 Qls[64 * KW];
    __shared__ __align__(16) u16 Khs[2][64 * KW];
    __shared__ __align__(16) u16 Kls[2][64 * KW];
    __shared__ __align__(16) u16 Vts[2][64 * 64];  // chunk-XOR: [v*64 + ((m>>3)^(v>>3))*8 + (m&7)]
    __shared__ __align__(16) u16 Ss [64 * SW];

    const int t    = threadIdx.x;
    const int lane = t & 63;
    const int w    = t >> 6;
    const int rb   = w >> 1;       // 0..3 : 16-row strip
    const int cb   = w & 1;        // 0..1 : 32-col strip
    const int nt   = blockIdx.x;
    const int b    = blockIdx.y;
    const int n0   = nt * 64;
    const long long bbase = (long long)b * SEQ;

    const int srow   = t >> 3;           // 0..63
    const int scol   = (t & 7) * 8;
    const int vchunk = ((srow >> 3) ^ (t & 7)) & 7;   // hoisted XOR for V store
    const int vrbase = vchunk * 8 + (srow & 7);

    // ---- prologue: stage Q and first K/V tile ----
    const int mt0 = (nt >= WT) ? (nt - WT) : 0;
    {
        *reinterpret_cast<u16x8*>(&Qhs[srow * KW + scol]) =
            *reinterpret_cast<const u16x8*>(&Qh16[(bbase + n0 + srow) * HD + scol]);
        *reinterpret_cast<u16x8*>(&Qls[srow * KW + scol]) =
            *reinterpret_cast<const u16x8*>(&Ql16[(bbase + n0 + srow) * HD + scol]);
        const long long g = (bbase + mt0 * 64 + srow) * HD + scol;
        *reinterpret_cast<u16x8*>(&Khs[0][srow * KW + scol]) =
            *reinterpret_cast<const u16x8*>(&Kh16[g]);
        *reinterpret_cast<u16x8*>(&Kls[0][srow * KW + scol]) =
            *reinterpret_cast<const u16x8*>(&Kl16[g]);
        const u16x8 vv = *reinterpret_cast<const u16x8*>(&Vb[g]);
#pragma unroll
        for (int j = 0; j < 8; ++j)
            Vts[0][(scol + j) * 64 + vrbase] = vv[j];
    }
    __syncthreads();

    // hoisted Q fragments
    const int frow = rb * 16 + (lane & 15);
    const int fk   = (lane >> 4) * 8;
    const bf16x8 qh0 = *reinterpret_cast<const bf16x8*>(&Qhs[frow * KW + fk]);
    const bf16x8 qh1 = *reinterpret_cast<const bf16x8*>(&Qhs[frow * KW + 32 + fk]);
    const bf16x8 ql0 = *reinterpret_cast<const bf16x8*>(&Qls[frow * KW + fk]);
    const bf16x8 ql1 = *reinterpret_cast<const bf16x8*>(&Qls[frow * KW + 32 + fk]);

    f32x4 accO[2];
    accO[0] = (f32x4)0.f; accO[1] = (f32x4)0.f;

    const float log2g = -0.04580368544f;   // log2(0.96875)

    for (int mt = mt0; mt <= nt; ++mt) {
        const int cur  = (mt - mt0) & 1;
        const int m0   = mt * 64;
        const bool pref = (mt < nt);

        // 1. issue next-tile global loads (in flight under QK^T)
        u16x8 pk_h, pk_l, pv;
        if (pref) {
            const long long g = (bbase + m0 + 64 + srow) * HD + scol;
            pk_h = *reinterpret_cast<const u16x8*>(&Kh16[g]);
            pk_l = *reinterpret_cast<const u16x8*>(&Kl16[g]);
            pv   = *reinterpret_cast<const u16x8*>(&Vb[g]);
        }

        // 2. S = Q K^T (hi/lo 3-term) from buf[cur]
        f32x4 accS[2];
        accS[0] = (f32x4)0.f; accS[1] = (f32x4)0.f;
#pragma unroll
        for (int ms = 0; ms < 2; ++ms) {
            const int mrow = (cb * 2 + ms) * 16 + (lane & 15);
            const bf16x8 kh0 = *reinterpret_cast<const bf16x8*>(&Khs[cur][mrow * KW + fk]);
            const bf16x8 kh1 = *reinterpret_cast<const bf16x8*>(&Khs[cur][mrow * KW + 32 + fk]);
            const bf16x8 kl0 = *reinterpret_cast<const bf16x8*>(&Kls[cur][mrow * KW + fk]);
            const bf16x8 kl1 = *reinterpret_cast<const bf16x8*>(&Kls[cur][mrow * KW + 32 + fk]);
            accS[ms] = __builtin_amdgcn_mfma_f32_16x16x32_bf16(qh0, kh0, accS[ms], 0, 0, 0);
            accS[ms] = __builtin_amdgcn_mfma_f32_16x16x32_bf16(qh1, kh1, accS[ms], 0, 0, 0);
            accS[ms] = __builtin_amdgcn_mfma_f32_16x16x32_bf16(ql0, kh0, accS[ms], 0, 0, 0);
            accS[ms] = __builtin_amdgcn_mfma_f32_16x16x32_bf16(ql1, kh1, accS[ms], 0, 0, 0);
            accS[ms] = __builtin_amdgcn_mfma_f32_16x16x32_bf16(qh0, kl0, accS[ms], 0, 0, 0);
            accS[ms] = __builtin_amdgcn_mfma_f32_16x16x32_bf16(qh1, kl1, accS[ms], 0, 0, 0);
        }

        // 3. decay + mask + bf16 -> Ss (stride 68: conflict-free)
#pragma unroll
        for (int ms = 0; ms < 2; ++ms) {
            const int mloc = (cb * 2 + ms) * 16 + (lane & 15);
            const int dm   = (n0 - m0) - mloc;
#pragma unroll
            for (int reg = 0; reg < 4; ++reg) {
                const int nloc = rb * 16 + (lane >> 4) * 4 + reg;
                const int d    = dm + nloc;
                const float g  = (d >= 0) ? exp2f((float)d * log2g) : 0.f;
                Ss[nloc * SW + mloc] = f2bf(accS[ms][reg] * g);
            }
        }

        // 4. write prefetched K/V -> buf[cur^1]
        if (pref) {
            *reinterpret_cast<u16x8*>(&Khs[cur ^ 1][srow * KW + scol]) = pk_h;
            *reinterpret_cast<u16x8*>(&Kls[cur ^ 1][srow * KW + scol]) = pk_l;
#pragma unroll
            for (int j = 0; j < 8; ++j)
                Vts[cur ^ 1][(scol + j) * 64 + vrbase] = pv[j];
        }

        __syncthreads();   // B1: Ss ready; next K/V staged

        // 6. O += S V from Ss + Vts[cur]
        const bf16x8 s0 = ld_s8(&Ss[frow * SW + fk]);
        const bf16x8 s1 = ld_s8(&Ss[frow * SW + 32 + fk]);
#pragma unroll
        for (int vv = 0; vv < 2; ++vv) {
            const int vrow = cb * 32 + vv * 16 + (lane & 15);
            const int c0 = ((lane >> 4)     ^ (vrow >> 3)) & 7;
            const int c1 = (((lane >> 4) + 4) ^ (vrow >> 3)) & 7;
            const bf16x8 v0 = *reinterpret_cast<const bf16x8*>(&Vts[cur][vrow * 64 + c0 * 8]);
            const bf16x8 v1 = *reinterpret_cast<const bf16x8*>(&Vts[cur][vrow * 64 + c1 * 8]);
            accO[vv] = __builtin_amdgcn_mfma_f32_16x16x32_bf16(s0, v0, accO[vv], 0, 0, 0);
            accO[vv] = __builtin_amdgcn_mfma_f32_16x16x32_bf16(s1, v1, accO[vv], 0, 0, 0);
        }

        __syncthreads();   // B2: SV reads done -> Ss/Vts reusable
    }

#pragma unroll
    for (int vv = 0; vv < 2; ++vv) {
        const int v = cb * 32 + vv * 16 + (lane & 15);
#pragma unroll
        for (int reg = 0; reg < 4; ++reg) {
            const int n = n0 + rb * 16 + (lane >> 4) * 4 + reg;
            Out[(bbase + n) * HD + v] = accO[vv][reg];
        }
    }
}

// ---------------------------------------------------------------------------
extern "C" void kernel_launch(void* const* d_in, const int* in_sizes, int n_in,
                              void* d_out, int out_size, void* d_ws, size_t ws_size,
                              hipStream_t stream)
{
    const float* X  = (const float*)d_in[0];
    const float* WQ = (const float*)d_in[1];
    const float* WK = (const float*)d_in[2];
    const float* WV = (const float*)d_in[3];
    float* Out = (float*)d_out;

    char* ws = (char*)d_ws;
    const size_t SZ = (size_t)NB * SEQ * HD * sizeof(u16);   // 2 MB
    u16* Qh = (u16*)(ws);
    u16* Ql = (u16*)(ws + SZ);
    u16* Kh = (u16*)(ws + 2 * SZ);
    u16* Kl = (u16*)(ws + 3 * SZ);
    u16* Vb = (u16*)(ws + 4 * SZ);
    float* Tbl = (float*)(ws + 5 * SZ);                      // 2 MB
    u16* Wfh = (u16*)(ws + 6 * SZ);                          // 96 KB (pad 128K)
    u16* Wfl = (u16*)(ws + 6 * SZ + (128 << 10));

    prep_kernel<<<dim3(536), 256, 0, stream>>>(WQ, WK, WV, Tbl, Wfh, Wfl);
    proj_kernel<<<dim3(256), 512, 0, stream>>>(
        X, Tbl, Wfh, Wfl, Qh, Ql, Kh, Kl, Vb);
    retention_kernel<<<dim3(SEQ / 64, NB), 512, 0, stream>>>(
        Qh, Ql, Kh, Kl, Vb, Out);
}

// Round 5
// 37.334 us; speedup vs baseline: 7.4451x; 1.1351x over previous
//
#include <hip/hip_runtime.h>
#include <hip/hip_bf16.h>
#include <math.h>

// SimpleRetention on MI355X, round 5.
// out = (Q K^T ∘ D) V, D[n,m]=gamma^(n-m)[n>=m], gamma=0.96875.
// Banded: gamma^513 ~ 8e-8 -> window of 8 previous 64-tiles + diagonal.
// proj v4: X->bf16 hi/lo converted ONCE to LDS, 4 waves/SIMD, paired u32 emit.
// retention v3: 16 waves (4/SIMD), stride-72 LDS (all frag reads <=2-way),
//               LUT decay (no exp2f in loop), K/V dbuf prefetch, XCD swizzle.

#define SEQ    4096
#define NB     4
#define HID    256
#define HD     64
#define WT     8

typedef short          bf16x8 __attribute__((ext_vector_type(8)));
typedef float          f32x4  __attribute__((ext_vector_type(4)));
typedef unsigned short u16;
typedef unsigned int   u32;
typedef u16            u16x8  __attribute__((ext_vector_type(8)));
typedef u16            u16x4  __attribute__((ext_vector_type(4)));

__device__ __forceinline__ u16 f2bf(float f) {
    __hip_bfloat16 h = __float2bfloat16(f);
    return __builtin_bit_cast(u16, h);
}
__device__ __forceinline__ float bf2f(u16 b) {
    __hip_bfloat16 h = __builtin_bit_cast(__hip_bfloat16, b);
    return __bfloat162float(h);
}

// ---------------------------------------------------------------------------
// Prep: xPos table (blocks 0..511) + W fragment swizzle hi/lo (blocks 512..535).
// Wf frag f = ((ct*8 + kc)*64 + lane): b[j] = W[kc*32+(lane>>4)*8+j][ct*16+(lane&15)]
// ---------------------------------------------------------------------------
__global__ __launch_bounds__(256)
void prep_kernel(const float* __restrict__ WQ, const float* __restrict__ WK,
                 const float* __restrict__ WV, float* __restrict__ Tbl,
                 u16* __restrict__ Wfh, u16* __restrict__ Wfl)
{
    const int t = threadIdx.x;
    if (blockIdx.x < 512) {
        const int p = blockIdx.x * 256 + t;
        const int n = p >> 5, i = p & 31;
        const float sv = (2.f * (float)i + 25.6f) / 89.6f;
        const float sc = powf(sv, (float)n * (1.f / 512.f));
        const float inv_freq = 1.f / powf(10000.f, (float)i * (1.f / 32.f));
        float sn, cs;
        sincosf((float)n * inv_freq, &sn, &cs);
        float4 o;
        o.x = cs * sc; o.y = sn * sc;   // Q (downscale=False)
        o.z = cs / sc; o.w = sn / sc;   // K (downscale=True)
        reinterpret_cast<float4*>(Tbl)[p] = o;
    } else {
        const int p = (blockIdx.x - 512) * 256 + t;   // 0..6143
        const int lane = p & 63;
        const int kc   = (p >> 6) & 7;
        const int ct   = p >> 9;                      // 0..11
        const int col  = ct * 16 + (lane & 15);
        const float* Wsrc = (col < 64) ? WQ : (col < 128) ? WK : WV;
        const int c = col & 63;
        u16x8 hv, lv;
#pragma unroll
        for (int j = 0; j < 8; ++j) {
            const float w = Wsrc[(kc * 32 + (lane >> 4) * 8 + j) * HD + c];
            hv[j] = f2bf(w);
            lv[j] = f2bf(w - bf2f(hv[j]));
        }
        *reinterpret_cast<u16x8*>(&Wfh[(size_t)p * 8]) = hv;
        *reinterpret_cast<u16x8*>(&Wfl[(size_t)p * 8]) = lv;
    }
}

// ---------------------------------------------------------------------------
// Projection + fused xPos. 512 blocks x 512 thr, 32 rows/block.
// X converted to hi/lo bf16 once into LDS; waves read b128 A-frags.
// ---------------------------------------------------------------------------
#define XLDS 264   // u16 row stride: 16B-aligned, 2-way bank alias (free)

__global__ __launch_bounds__(512, 4)
void proj_kernel(const float* __restrict__ X, const float* __restrict__ Tbl,
                 const u16* __restrict__ Wfh, const u16* __restrict__ Wfl,
                 u16* __restrict__ Qh, u16* __restrict__ Ql,
                 u16* __restrict__ Kh, u16* __restrict__ Kl,
                 u16* __restrict__ Vb)
{
    __shared__ __align__(16) u16 Xhs[32 * XLDS];
    __shared__ __align__(16) u16 Xls[32 * XLDS];
    const int t = threadIdx.x;
    const int row0 = blockIdx.x * 32;

    // stage X tile as bf16 hi/lo (convert once per block)
    for (int e = t; e < 32 * 64; e += 512) {
        const int r = e >> 6, k4 = (e & 63) << 2;
        const float4 xv = *reinterpret_cast<const float4*>(&X[(size_t)(row0 + r) * HID + k4]);
        u16x4 hv, lv;
#pragma unroll
        for (int j = 0; j < 4; ++j) {
            const float f = (&xv.x)[j];
            hv[j] = f2bf(f);
            lv[j] = f2bf(f - bf2f(hv[j]));
        }
        *reinterpret_cast<u16x4*>(&Xhs[r * XLDS + k4]) = hv;
        *reinterpret_cast<u16x4*>(&Xls[r * XLDS + k4]) = lv;
    }
    __syncthreads();

    const int lane = t & 63;
    const int w    = t >> 6;
    const int rt   = w >> 2;    // 0..1 : 16-row tile
    const int ch   = w & 3;     // 0..3 : 3 col-tiles each
    const int frow = rt * 16 + (lane & 15);
    const int fk   = (lane >> 4) * 8;

    f32x4 acc[3];
#pragma unroll
    for (int i = 0; i < 3; ++i) acc[i] = (f32x4)0.f;

    for (int kc = 0; kc < 8; ++kc) {
        const bf16x8 ah = *reinterpret_cast<const bf16x8*>(&Xhs[frow * XLDS + kc * 32 + fk]);
        const bf16x8 al = *reinterpret_cast<const bf16x8*>(&Xls[frow * XLDS + kc * 32 + fk]);
#pragma unroll
        for (int ctp = 0; ctp < 3; ++ctp) {
            const int ct = ch * 3 + ctp;
            const size_t fb = (size_t)((ct * 8 + kc) * 64 + lane) * 8;
            const bf16x8 wh = *reinterpret_cast<const bf16x8*>(&Wfh[fb]);
            const bf16x8 wl = *reinterpret_cast<const bf16x8*>(&Wfl[fb]);
            acc[ctp] = __builtin_amdgcn_mfma_f32_16x16x32_bf16(ah, wh, acc[ctp], 0, 0, 0);
            acc[ctp] = __builtin_amdgcn_mfma_f32_16x16x32_bf16(al, wh, acc[ctp], 0, 0, 0);
            acc[ctp] = __builtin_amdgcn_mfma_f32_16x16x32_bf16(ah, wl, acc[ctp], 0, 0, 0);
        }
    }

    // emit: pair adjacent columns (2i,2i+1) -> u32 stores.
    // even lanes handle regs 0-1, odd lanes regs 2-3 (both columns of the pair).
    const int grow0 = row0 + rt * 16;
    const int sel   = lane & 1;
    const int c16   = lane & 15;
    const int rbase = (lane >> 4) * 4;

#pragma unroll
    for (int ctp = 0; ctp < 3; ++ctp) {
        const int ct = ch * 3 + ctp;
        float xp[4];
#pragma unroll
        for (int reg = 0; reg < 4; ++reg)
            xp[reg] = __shfl_xor(acc[ctp][reg], 1, 64);
#pragma unroll
        for (int rr = 0; rr < 2; ++rr) {
            const int reg = sel * 2 + rr;
            const float xe = sel ? xp[reg] : acc[ctp][reg];   // even-col value
            const float xo = sel ? acc[ctp][reg] : xp[reg];   // odd-col value
            const int r = grow0 + rbase + reg;
            if (ct < 8) {
                const bool isK = ct >= 4;
                const int cq0 = (ct & 3) * 16 + (c16 & ~1);
                const int i   = cq0 >> 1;
                const int n   = r & (SEQ - 1);
                const float4 tb = reinterpret_cast<const float4*>(Tbl)[n * 32 + i];
                const float cs = isK ? tb.z : tb.x;
                const float sn = isK ? tb.w : tb.y;
                const float oe = xe * cs - xo * sn;
                const float oo = xo * cs + xe * sn;
                const u16 he = f2bf(oe), ho = f2bf(oo);
                const u32 hw = (u32)he | ((u32)ho << 16);
                const u32 lw = (u32)f2bf(oe - bf2f(he)) | ((u32)f2bf(oo - bf2f(ho)) << 16);
                u32* Ph = reinterpret_cast<u32*>(isK ? Kh : Qh);
                u32* Pl = reinterpret_cast<u32*>(isK ? Kl : Ql);
                Ph[(r * HD + cq0) >> 1] = hw;
                Pl[(r * HD + cq0) >> 1] = lw;
            } else {
                const int cv0 = (ct - 8) * 16 + (c16 & ~1);
                const u32 w32 = (u32)f2bf(xe) | ((u32)f2bf(xo) << 16);
                reinterpret_cast<u32*>(Vb)[(r * HD + cv0) >> 1] = w32;
            }
        }
    }
}

// ---------------------------------------------------------------------------
// Banded retention. 256 blocks x 1024 thr (16 waves, 4/SIMD).
// Wave (rb,cb) owns the 16x16 S/O tile at rows rb*16, cols cb*16.
// LDS strides: 72 (Q/K/V: frag reads <=2-way), 68 (S: conflict-free).
// V layout: Vts[v*72 + ((m>>3 ^ v>>3)&7)*8 + (m&7)]  (chunk-XOR, b128 reads).
// ---------------------------------------------------------------------------
#define KRS 72
#define SW  68

__device__ __forceinline__ bf16x8 ld_s8(const u16* p) {
    const u16x4 lo = *reinterpret_cast<const u16x4*>(p);
    const u16x4 hi = *reinterpret_cast<const u16x4*>(p + 4);
    bf16x8 r;
#pragma unroll
    for (int j = 0; j < 4; ++j) { r[j] = (short)lo[j]; r[4 + j] = (short)hi[j]; }
    return r;
}

__global__ __launch_bounds__(1024)
void retention_kernel(const u16* __restrict__ Qh16, const u16* __restrict__ Ql16,
                      const u16* __restrict__ Kh16, const u16* __restrict__ Kl16,
                      const u16* __restrict__ Vb, float* __restrict__ Out)
{
    __shared__ __align__(16) u16 Qhs[64 * KRS];
    __shared__ __align__(16) u16 Qls[64 * KRS];
    __shared__ __align__(16) u16 Khs[2][64 * KRS];
    __shared__ __align__(16) u16 Kls[2][64 * KRS];
    __shared__ __align__(16) u16 Vts[2][64 * KRS];
    __shared__ __align__(16) u16 Ss [64 * SW];

    const int t    = threadIdx.x;
    const int lane = t & 63;
    const int w    = t >> 6;       // 0..15
    const int rb   = w >> 2;       // 0..3 : 16-row strip of S/O
    const int cb   = w & 3;        // 0..3 : 16-col strip

    // XCD swizzle: contiguous nt chunks per XCD (256 blocks, 8 XCDs, bijective)
    const int flat = blockIdx.x + 64 * blockIdx.y;
    const int work = (flat & 7) * 32 + (flat >> 3);
    const int nt   = work & 63;
    const int b    = work >> 6;
    const int n0   = nt * 64;
    const int bbase = b * SEQ;

    // staging roles: half 0 -> K hi/lo (and Q hi); half 1 -> V (and Q lo)
    const int half = t >> 9;
    const int th   = t & 511;
    const int srow = th >> 3;           // 0..63
    const int scol = (th & 7) * 8;
    const int vch  = ((srow >> 3) ^ (th & 7)) & 7;   // (m>>3) ^ (v>>3)

    const int mt0 = (nt >= WT) ? (nt - WT) : 0;

    // ---- prologue: Q + first K/V tile ----
    {
        const int gq = (bbase + n0 + srow) * HD + scol;
        const int gk = (bbase + mt0 * 64 + srow) * HD + scol;
        if (half == 0) {
            *reinterpret_cast<u16x8*>(&Qhs[srow * KRS + scol]) =
                *reinterpret_cast<const u16x8*>(&Qh16[gq]);
            *reinterpret_cast<u16x8*>(&Khs[0][srow * KRS + scol]) =
                *reinterpret_cast<const u16x8*>(&Kh16[gk]);
            *reinterpret_cast<u16x8*>(&Kls[0][srow * KRS + scol]) =
                *reinterpret_cast<const u16x8*>(&Kl16[gk]);
        } else {
            *reinterpret_cast<u16x8*>(&Qls[srow * KRS + scol]) =
                *reinterpret_cast<const u16x8*>(&Ql16[gq]);
            const u16x8 vv = *reinterpret_cast<const u16x8*>(&Vb[gk]);
#pragma unroll
            for (int j = 0; j < 8; ++j)
                Vts[0][(scol + j) * KRS + vch * 8 + (srow & 7)] = vv[j];
        }
    }
    __syncthreads();

    // hoisted Q fragments
    const int frow = rb * 16 + (lane & 15);
    const int fk   = (lane >> 4) * 8;
    const bf16x8 qh0 = *reinterpret_cast<const bf16x8*>(&Qhs[frow * KRS + fk]);
    const bf16x8 qh1 = *reinterpret_cast<const bf16x8*>(&Qhs[frow * KRS + 32 + fk]);
    const bf16x8 ql0 = *reinterpret_cast<const bf16x8*>(&Qls[frow * KRS + fk]);
    const bf16x8 ql1 = *reinterpret_cast<const bf16x8*>(&Qls[frow * KRS + 32 + fk]);

    // per-lane decay constants: gamma^d = gamma^(n0-m0) * gamma^(nloc-mloc)
    const float log2g = -0.04580368544f;   // log2(0.96875)
    const int nlocB = rb * 16 + (lane >> 4) * 4;
    const int mloc  = cb * 16 + (lane & 15);
    float gd[4]; int dd[4];
#pragma unroll
    for (int reg = 0; reg < 4; ++reg) {
        dd[reg] = nlocB + reg - mloc;
        gd[reg] = exp2f((float)dd[reg] * log2g);
    }

    f32x4 accO = (f32x4)0.f;
    const int mrow = cb * 16 + (lane & 15);
    const int c0 = ((lane >> 4)     ^ (mrow >> 3)) & 7;
    const int c1 = (((lane >> 4) + 4) ^ (mrow >> 3)) & 7;

    for (int mt = mt0; mt <= nt; ++mt) {
        const int cur  = (mt - mt0) & 1;
        const int m0   = mt * 64;
        const bool pref = (mt < nt);

        // 1. issue next-tile global loads (in flight under QK^T)
        u16x8 pk_h, pk_l, pv;
        if (pref) {
            const int gk = (bbase + m0 + 64 + srow) * HD + scol;
            if (half == 0) {
                pk_h = *reinterpret_cast<const u16x8*>(&Kh16[gk]);
                pk_l = *reinterpret_cast<const u16x8*>(&Kl16[gk]);
            } else {
                pv = *reinterpret_cast<const u16x8*>(&Vb[gk]);
            }
        }

        // 2. S = Q K^T (hi/lo 3-term), 16x16 per wave
        const bf16x8 kh0 = *reinterpret_cast<const bf16x8*>(&Khs[cur][mrow * KRS + fk]);
        const bf16x8 kh1 = *reinterpret_cast<const bf16x8*>(&Khs[cur][mrow * KRS + 32 + fk]);
        const bf16x8 kl0 = *reinterpret_cast<const bf16x8*>(&Kls[cur][mrow * KRS + fk]);
        const bf16x8 kl1 = *reinterpret_cast<const bf16x8*>(&Kls[cur][mrow * KRS + 32 + fk]);
        f32x4 accS = (f32x4)0.f;
        accS = __builtin_amdgcn_mfma_f32_16x16x32_bf16(qh0, kh0, accS, 0, 0, 0);
        accS = __builtin_amdgcn_mfma_f32_16x16x32_bf16(qh1, kh1, accS, 0, 0, 0);
        accS = __builtin_amdgcn_mfma_f32_16x16x32_bf16(ql0, kh0, accS, 0, 0, 0);
        accS = __builtin_amdgcn_mfma_f32_16x16x32_bf16(ql1, kh1, accS, 0, 0, 0);
        accS = __builtin_amdgcn_mfma_f32_16x16x32_bf16(qh0, kl0, accS, 0, 0, 0);
        accS = __builtin_amdgcn_mfma_f32_16x16x32_bf16(qh1, kl1, accS, 0, 0, 0);

        // 3. decay + mask + bf16 -> Ss
        const float gs = exp2f((float)(n0 - m0) * log2g);
#pragma unroll
        for (int reg = 0; reg < 4; ++reg) {
            const int d   = (n0 - m0) + dd[reg];
            const float g = (d >= 0) ? gs * gd[reg] : 0.f;
            Ss[(nlocB + reg) * SW + mloc] = f2bf(accS[reg] * g);
        }

        // 4. write prefetched K/V -> buf[cur^1]
        if (pref) {
            if (half == 0) {
                *reinterpret_cast<u16x8*>(&Khs[cur ^ 1][srow * KRS + scol]) = pk_h;
                *reinterpret_cast<u16x8*>(&Kls[cur ^ 1][srow * KRS + scol]) = pk_l;
            } else {
#pragma unroll
                for (int j = 0; j < 8; ++j)
                    Vts[cur ^ 1][(scol + j) * KRS + vch * 8 + (srow & 7)] = pv[j];
            }
        }

        __syncthreads();   // B1: Ss ready; next K/V staged

        // 5. O += S V
        const bf16x8 s0 = ld_s8(&Ss[frow * SW + fk]);
        const bf16x8 s1 = ld_s8(&Ss[frow * SW + 32 + fk]);
        const bf16x8 v0 = *reinterpret_cast<const bf16x8*>(&Vts[cur][mrow * KRS + c0 * 8]);
        const bf16x8 v1 = *reinterpret_cast<const bf16x8*>(&Vts[cur][mrow * KRS + c1 * 8]);
        accO = __builtin_amdgcn_mfma_f32_16x16x32_bf16(s0, v0, accO, 0, 0, 0);
        accO = __builtin_amdgcn_mfma_f32_16x16x32_bf16(s1, v1, accO, 0, 0, 0);

        __syncthreads();   // B2: SV reads done -> Ss/Vts reusable
    }

    // write output (fp32)
    const int v = cb * 16 + (lane & 15);
#pragma unroll
    for (int reg = 0; reg < 4; ++reg) {
        const int n = n0 + rb * 16 + (lane >> 4) * 4 + reg;
        Out[(size_t)(bbase + n) * HD + v] = accO[reg];
    }
}

// ---------------------------------------------------------------------------
extern "C" void kernel_launch(void* const* d_in, const int* in_sizes, int n_in,
                              void* d_out, int out_size, void* d_ws, size_t ws_size,
                              hipStream_t stream)
{
    const float* X  = (const float*)d_in[0];
    const float* WQ = (const float*)d_in[1];
    const float* WK = (const float*)d_in[2];
    const float* WV = (const float*)d_in[3];
    float* Out = (float*)d_out;

    char* ws = (char*)d_ws;
    const size_t SZ = (size_t)NB * SEQ * HD * sizeof(u16);   // 2 MB
    u16* Qh = (u16*)(ws);
    u16* Ql = (u16*)(ws + SZ);
    u16* Kh = (u16*)(ws + 2 * SZ);
    u16* Kl = (u16*)(ws + 3 * SZ);
    u16* Vb = (u16*)(ws + 4 * SZ);
    float* Tbl = (float*)(ws + 5 * SZ);                      // 2 MB
    u16* Wfh = (u16*)(ws + 6 * SZ);                          // 96 KB (pad 128K)
    u16* Wfl = (u16*)(ws + 6 * SZ + (128 << 10));

    prep_kernel<<<dim3(536), 256, 0, stream>>>(WQ, WK, WV, Tbl, Wfh, Wfl);
    proj_kernel<<<dim3(512), 512, 0, stream>>>(
        X, Tbl, Wfh, Wfl, Qh, Ql, Kh, Kl, Vb);
    retention_kernel<<<dim3(64, NB), 1024, 0, stream>>>(
        Qh, Ql, Kh, Kl, Vb, Out);
}